// Round 16
// baseline (213.331 us; speedup 1.0000x reference)
//
#include <hip/hip_runtime.h>

#define N_NODES 100000
#define N_EDGES 1600000
#define NB 391            // ceil(N_NODES/256) row-buckets of 256 rows
#define NBLK 1024         // blocks for binning pass (4x for latency hiding)
#define CHUNK 1563        // ceil(N_EDGES/NBLK)
#define CAP 5120          // per-bucket binbuf capacity (mean 4096, sigma 64)

typedef unsigned int uint;
typedef __attribute__((ext_vector_type(8))) short short8v;  // 8 bf16 (4 VGPRs)
typedef __attribute__((ext_vector_type(4))) float f32x4;

// ---------------- bf16 helpers ----------------

__device__ __forceinline__ uint bfrn(float x) {  // fp32 -> bf16 bits (RN)
  uint u = __float_as_uint(x);
  u += 0x7fffu + ((u >> 16) & 1u);
  return u >> 16;
}
__device__ __forceinline__ uint bfpack(float a, float b) {
  return bfrn(a) | (bfrn(b) << 16);
}
__device__ __forceinline__ float bflo(uint u) { return __uint_as_float(u << 16); }
__device__ __forceinline__ float bfhi(uint u) { return __uint_as_float(u & 0xffff0000u); }

// ---------------- kernel A: binning (blocks 0..NBLK-1) + weight packs ------------
// gcur zero-init by hipMemsetAsync; reservation slot = i*CAP + atomicAdd(gcur[i],c).
// Packed B-fragment index for element (k,f), NCT=FOUT/16:
//   ks=k>>5, j=k&7, lq=(k>>3)&3, lane=(lq<<4)|(f&15), ct=f>>4
//   idx = ((ks*NCT + ct)*64 + lane)*8 + j

__global__ __launch_bounds__(256) void combo_k(const int* __restrict__ ei,
                                               int* __restrict__ gcur,
                                               unsigned* __restrict__ binbuf,
                                               const float* __restrict__ W0,
                                               const float* __restrict__ W1,
                                               const float* __restrict__ W2,
                                               unsigned short* __restrict__ W01p,
                                               unsigned short* __restrict__ W2p) {
  int b = blockIdx.x;
  if (b < NBLK) {
    __shared__ int lh[NB];
    __shared__ int rstage[CHUNK];  // ~6.2 KB: stage r to avoid global re-read
    for (int i = threadIdx.x; i < NB; i += 256) lh[i] = 0;
    __syncthreads();
    int ebeg = b * CHUNK;
    int n = min(CHUNK, N_EDGES - ebeg);
    for (int t = threadIdx.x; t < n; t += 256) {
      int r = ei[ebeg + t];
      rstage[t] = r;
      atomicAdd(&lh[r >> 8], 1);
    }
    __syncthreads();
    for (int i = threadIdx.x; i < NB; i += 256) {
      int c = lh[i];
      lh[i] = c ? (i * CAP + atomicAdd(&gcur[i], c)) : 0;
    }
    __syncthreads();
    for (int t = threadIdx.x; t < n; t += 256) {
      int r = rstage[t];
      int c = ei[N_EDGES + ebeg + t];
      int p = atomicAdd(&lh[r >> 8], 1);
      binbuf[p] = ((unsigned)(r & 255) << 24) | (unsigned)c;  // c < 2^17 fits
    }
  } else if (b < NBLK + 64) {
    int g = (b - NBLK) * 256 + threadIdx.x;  // 16384: W01 = W0@W1
    int k = g >> 7, f = g & 127;
    float s = 0.f;
    for (int kk = 0; kk < 128; kk++) s = fmaf(W0[k * 128 + kk], W1[kk * 128 + f], s);
    int ks = k >> 5, j = k & 7, lq = (k >> 3) & 3;
    int lane = (lq << 4) | (f & 15), ct = f >> 4;
    W01p[((ks * 8 + ct) * 64 + lane) * 8 + j] = (unsigned short)bfrn(s);
  } else {
    int g = (b - NBLK - 64) * 256 + threadIdx.x;  // 8192: W2
    int k = g >> 6, f = g & 63;
    int ks = k >> 5, j = k & 7, lq = (k >> 3) & 3;
    int lane = (lq << 4) | (f & 15), ct = f >> 4;
    W2p[((ks * 4 + ct) * 64 + lane) * 8 + j] = (unsigned short)bfrn(W2[k * 64 + f]);
  }
}

// ---------------- kernel B: per-bucket CSR build; bucket edges staged in LDS ------

__global__ __launch_bounds__(256) void buckoff_k(const unsigned* __restrict__ binbuf,
                                                 const int* __restrict__ gcur,
                                                 int* __restrict__ off,
                                                 float* __restrict__ dinv,
                                                 uint* __restrict__ cc) {
  __shared__ unsigned est[CAP];  // 20 KB: this bucket's edges
  __shared__ int cnt[256];
  __shared__ int sc[256];
  __shared__ int sbase_s;
  int k = blockIdx.x, row0n = k << 8, tid = threadIdx.x;
  if (tid < 64) {  // sbase = sum_{j<k} count_j
    int s = 0;
    for (int j = tid; j < k; j += 64) s += gcur[j];
#pragma unroll
    for (int d = 32; d; d >>= 1) s += __shfl_xor(s, d);
    if (tid == 0) sbase_s = s;
  }
  cnt[tid] = 0;
  __syncthreads();
  int n = gcur[k];
  int sb = k * CAP;
  for (int t = tid; t < n; t += 256) {  // single global read of the bucket
    unsigned u = binbuf[sb + t];
    est[t] = u;
    atomicAdd(&cnt[u >> 24], 1);
  }
  __syncthreads();
  int v = cnt[tid];
  sc[tid] = v;
  __syncthreads();
  for (int d = 1; d < 256; d <<= 1) {
    int t = (tid >= d) ? sc[tid - d] : 0;
    __syncthreads();
    sc[tid] += t;
    __syncthreads();
  }
  int row = row0n + tid;
  int mystart = sbase_s + sc[tid] - v;
  if (row < N_NODES) {
    off[row] = mystart;
    dinv[row] = rsqrtf((float)v + 1.0f);  // +1 = self-loop
  }
  if (k == NB - 1 && tid == 0) off[N_NODES] = N_EDGES;
  __syncthreads();
  cnt[tid] = mystart;  // reuse as placement cursor
  __syncthreads();
  for (int t = tid; t < n; t += 256) {
    unsigned u = est[t];
    int slot = atomicAdd(&cnt[u >> 24], 1);
    cc[slot] = u & 0xFFFFFFu;
  }
}

// ---------------- MFMA GEMM 128->128: x0b = bf16(dinv ⊙ (feat @ W01)) -------------

__global__ __launch_bounds__(256) void mgemm128_k(const float* __restrict__ feat,
                                                  const unsigned short* __restrict__ Wp,
                                                  unsigned short* __restrict__ Cb,
                                                  const float* __restrict__ dinv) {
  __shared__ uint4 Al4[64 * 16];    // 16 KB A tile (swizzled bf16)
  __shared__ uint4 Wl4[128 * 16];   // 32 KB packed W01 fragments
  char* Al = (char*)Al4;
  int tid = threadIdx.x;
  int row0 = blockIdx.x * 64;
  for (int i = tid; i < 128 * 16; i += 256) Wl4[i] = ((const uint4*)Wp)[i];
  const float4* Af = (const float4*)feat;
  for (int i = tid; i < 64 * 32; i += 256) {
    int r = i >> 5, c4 = i & 31;
    int gr = row0 + r;
    float4 vv = make_float4(0.f, 0.f, 0.f, 0.f);
    if (gr < N_NODES) vv = Af[(uint)gr * 32u + c4];
    uint2 p;
    p.x = bfpack(vv.x, vv.y);
    p.y = bfpack(vv.z, vv.w);
    int byte = (r * 256 + c4 * 8) ^ ((r & 7) << 4);
    *(uint2*)(Al + byte) = p;
  }
  __syncthreads();
  int lane = tid & 63, w = tid >> 6;
  f32x4 acc[8];
#pragma unroll
  for (int ct = 0; ct < 8; ct++) acc[ct] = (f32x4){0.f, 0.f, 0.f, 0.f};
  int arow = w * 16 + (lane & 15);
#pragma unroll
  for (int ks = 0; ks < 4; ks++) {
    int abyte = (arow * 256 + ks * 64 + (lane >> 4) * 16) ^ ((arow & 7) << 4);
    short8v a = *(const short8v*)(Al + abyte);
#pragma unroll
    for (int ct = 0; ct < 8; ct++) {
      short8v bb = *(const short8v*)((const char*)Wl4 + ((ks * 8 + ct) * 64 + lane) * 16);
      acc[ct] = __builtin_amdgcn_mfma_f32_16x16x32_bf16(a, bb, acc[ct], 0, 0, 0);
    }
  }
#pragma unroll
  for (int j = 0; j < 4; j++) {
    int grow = row0 + w * 16 + ((lane >> 4) << 2) + j;
    if (grow < N_NODES) {
      float scale = dinv[grow];
#pragma unroll
      for (int ct = 0; ct < 8; ct++) {
        Cb[(uint)grow * 128u + ct * 16 + (lane & 15)] =
            (unsigned short)bfrn(acc[ct][j] * scale);
      }
    }
  }
}

// ---------------- prop, 128 bf16 feats, 4 edges/wave-load, 16-edge deep loop ------
// X pre-scaled (x' = dinv*x). grp = lane>>4 picks edge; o16 = lane&15 picks 8 feats.

template <bool RELU>
__global__ __launch_bounds__(256) void prop128q_k(const uint4* __restrict__ X4,  // bf16x8
                                                  uint4* __restrict__ Yb4,       // bf16x8
                                                  const int* __restrict__ off,
                                                  const uint* __restrict__ cc,
                                                  const float* __restrict__ dinv) {
  int node = blockIdx.x * 4 + (threadIdx.x >> 6);
  if (node >= N_NODES) return;
  uint lane = threadIdx.x & 63u;
  uint grp = lane >> 4, o16 = lane & 15u;
  float di = dinv[node];
  uint4 s = X4[(uint)node * 16u + o16];
  float a0 = 0.f, a1 = 0.f, a2 = 0.f, a3 = 0.f, a4 = 0.f, a5 = 0.f, a6 = 0.f, a7 = 0.f;
  int e = off[node], e1 = off[node + 1];
  for (; e + 15 < e1; e += 16) {  // 4 quads = 16 edges, 4 row-loads in flight
    uint c0 = cc[e + grp], c1 = cc[e + 4 + grp], c2 = cc[e + 8 + grp], c3 = cc[e + 12 + grp];
    uint4 v0 = X4[c0 * 16u + o16];
    uint4 v1 = X4[c1 * 16u + o16];
    uint4 v2 = X4[c2 * 16u + o16];
    uint4 v3 = X4[c3 * 16u + o16];
    a0 += bflo(v0.x) + bflo(v1.x) + bflo(v2.x) + bflo(v3.x);
    a1 += bfhi(v0.x) + bfhi(v1.x) + bfhi(v2.x) + bfhi(v3.x);
    a2 += bflo(v0.y) + bflo(v1.y) + bflo(v2.y) + bflo(v3.y);
    a3 += bfhi(v0.y) + bfhi(v1.y) + bfhi(v2.y) + bfhi(v3.y);
    a4 += bflo(v0.z) + bflo(v1.z) + bflo(v2.z) + bflo(v3.z);
    a5 += bfhi(v0.z) + bfhi(v1.z) + bfhi(v2.z) + bfhi(v3.z);
    a6 += bflo(v0.w) + bflo(v1.w) + bflo(v2.w) + bflo(v3.w);
    a7 += bfhi(v0.w) + bfhi(v1.w) + bfhi(v2.w) + bfhi(v3.w);
  }
  for (; e + 7 < e1; e += 8) {  // 2 quads
    uint c0 = cc[e + grp], c1 = cc[e + 4 + grp];
    uint4 v0 = X4[c0 * 16u + o16];
    uint4 v1 = X4[c1 * 16u + o16];
    a0 += bflo(v0.x) + bflo(v1.x);
    a1 += bfhi(v0.x) + bfhi(v1.x);
    a2 += bflo(v0.y) + bflo(v1.y);
    a3 += bfhi(v0.y) + bfhi(v1.y);
    a4 += bflo(v0.z) + bflo(v1.z);
    a5 += bfhi(v0.z) + bfhi(v1.z);
    a6 += bflo(v0.w) + bflo(v1.w);
    a7 += bfhi(v0.w) + bfhi(v1.w);
  }
  for (; e + 3 < e1; e += 4) {  // one quad
    uint c0 = cc[e + grp];
    uint4 v0 = X4[c0 * 16u + o16];
    a0 += bflo(v0.x); a1 += bfhi(v0.x);
    a2 += bflo(v0.y); a3 += bfhi(v0.y);
    a4 += bflo(v0.z); a5 += bfhi(v0.z);
    a6 += bflo(v0.w); a7 += bfhi(v0.w);
  }
  if (e + (int)grp < e1) {  // tail 1..3 edges: group-masked
    uint c0 = cc[e + grp];
    uint4 v0 = X4[c0 * 16u + o16];
    a0 += bflo(v0.x); a1 += bfhi(v0.x);
    a2 += bflo(v0.y); a3 += bfhi(v0.y);
    a4 += bflo(v0.z); a5 += bfhi(v0.z);
    a6 += bflo(v0.w); a7 += bfhi(v0.w);
  }
  a0 += __shfl_xor(a0, 16); a1 += __shfl_xor(a1, 16);
  a2 += __shfl_xor(a2, 16); a3 += __shfl_xor(a3, 16);
  a4 += __shfl_xor(a4, 16); a5 += __shfl_xor(a5, 16);
  a6 += __shfl_xor(a6, 16); a7 += __shfl_xor(a7, 16);
  a0 += __shfl_xor(a0, 32); a1 += __shfl_xor(a1, 32);
  a2 += __shfl_xor(a2, 32); a3 += __shfl_xor(a3, 32);
  a4 += __shfl_xor(a4, 32); a5 += __shfl_xor(a5, 32);
  a6 += __shfl_xor(a6, 32); a7 += __shfl_xor(a7, 32);
  a0 = (a0 + bflo(s.x)) * di; a1 = (a1 + bfhi(s.x)) * di;
  a2 = (a2 + bflo(s.y)) * di; a3 = (a3 + bfhi(s.y)) * di;
  a4 = (a4 + bflo(s.z)) * di; a5 = (a5 + bfhi(s.z)) * di;
  a6 = (a6 + bflo(s.w)) * di; a7 = (a7 + bfhi(s.w)) * di;
  if (RELU) {
    a0 = fmaxf(a0, 0.f); a1 = fmaxf(a1, 0.f); a2 = fmaxf(a2, 0.f); a3 = fmaxf(a3, 0.f);
    a4 = fmaxf(a4, 0.f); a5 = fmaxf(a5, 0.f); a6 = fmaxf(a6, 0.f); a7 = fmaxf(a7, 0.f);
  }
  if (lane < 16) {
    uint4 p;
    p.x = bfpack(a0, a1);
    p.y = bfpack(a2, a3);
    p.z = bfpack(a4, a5);
    p.w = bfpack(a6, a7);
    Yb4[(uint)node * 16u + o16] = p;
  }
}

// ---------------- MFMA GEMM: t2b[64 x 64] = x1b[64 x 128] @ W2, dinv epilogue -----

__global__ __launch_bounds__(256) void mgemm64_k(const unsigned short* __restrict__ Ab16,
                                                 const unsigned short* __restrict__ Wp,
                                                 unsigned short* __restrict__ Cb,
                                                 const float* __restrict__ dinv) {
  __shared__ uint4 Al4[64 * 16];  // 16 KB: 64 rows x 128 bf16 (swizzled)
  __shared__ uint4 Wl4[64 * 16];  // 16 KB packed W2 fragments
  char* Al = (char*)Al4;
  int tid = threadIdx.x;
  int row0 = blockIdx.x * 64;
  for (int i = tid; i < 64 * 16; i += 256) Wl4[i] = ((const uint4*)Wp)[i];
  const uint4* Ab = (const uint4*)Ab16;
  for (int i = tid; i < 64 * 16; i += 256) {
    int r = i >> 4, c8 = i & 15;
    int gr = row0 + r;
    uint4 v = make_uint4(0, 0, 0, 0);
    if (gr < N_NODES) v = Ab[(uint)gr * 16u + c8];
    int byte = (r * 256 + c8 * 16) ^ ((r & 7) << 4);
    *(uint4*)(Al + byte) = v;
  }
  __syncthreads();
  int lane = tid & 63, w = tid >> 6;
  f32x4 acc[4];
#pragma unroll
  for (int ct = 0; ct < 4; ct++) acc[ct] = (f32x4){0.f, 0.f, 0.f, 0.f};
  int arow = w * 16 + (lane & 15);
#pragma unroll
  for (int ks = 0; ks < 4; ks++) {
    int abyte = (arow * 256 + ks * 64 + (lane >> 4) * 16) ^ ((arow & 7) << 4);
    short8v a = *(const short8v*)(Al + abyte);
#pragma unroll
    for (int ct = 0; ct < 4; ct++) {
      short8v bb = *(const short8v*)((const char*)Wl4 + ((ks * 4 + ct) * 64 + lane) * 16);
      acc[ct] = __builtin_amdgcn_mfma_f32_16x16x32_bf16(a, bb, acc[ct], 0, 0, 0);
    }
  }
#pragma unroll
  for (int j = 0; j < 4; j++) {
    int grow = row0 + w * 16 + ((lane >> 4) << 2) + j;
    if (grow < N_NODES) {
      float scale = dinv[grow];
#pragma unroll
      for (int ct = 0; ct < 4; ct++) {
        Cb[(uint)grow * 64u + ct * 16 + (lane & 15)] =
            (unsigned short)bfrn(acc[ct][j] * scale);
      }
    }
  }
}

// ---------------- prop, 64 bf16 feats, 8 edges/wave-load (8 lanes x uint4) --------
// Row = 128 B = 8 lanes x 16 B. grp = lane>>3 (8 edges); o8 = lane&7 (8 feats).

__global__ __launch_bounds__(256) void prop64q8_k(const uint4* __restrict__ X4,  // bf16x8
                                                  float4* __restrict__ Y4,
                                                  const int* __restrict__ off,
                                                  const uint* __restrict__ cc,
                                                  const float* __restrict__ dinv) {
  int node = blockIdx.x * 4 + (threadIdx.x >> 6);
  if (node >= N_NODES) return;
  uint lane = threadIdx.x & 63u;
  uint grp = lane >> 3, o8 = lane & 7u;
  float di = dinv[node];
  uint4 s = X4[(uint)node * 8u + o8];
  float a0 = 0.f, a1 = 0.f, a2 = 0.f, a3 = 0.f, a4 = 0.f, a5 = 0.f, a6 = 0.f, a7 = 0.f;
  int e = off[node], e1 = off[node + 1];
  for (; e + 15 < e1; e += 16) {  // 2 x 8 edges, 2 row-loads in flight
    uint c0 = cc[e + grp], c1 = cc[e + 8 + grp];
    uint4 v0 = X4[c0 * 8u + o8];
    uint4 v1 = X4[c1 * 8u + o8];
    a0 += bflo(v0.x) + bflo(v1.x);
    a1 += bfhi(v0.x) + bfhi(v1.x);
    a2 += bflo(v0.y) + bflo(v1.y);
    a3 += bfhi(v0.y) + bfhi(v1.y);
    a4 += bflo(v0.z) + bflo(v1.z);
    a5 += bfhi(v0.z) + bfhi(v1.z);
    a6 += bflo(v0.w) + bflo(v1.w);
    a7 += bfhi(v0.w) + bfhi(v1.w);
  }
  for (; e + 7 < e1; e += 8) {  // 8 edges
    uint c0 = cc[e + grp];
    uint4 v0 = X4[c0 * 8u + o8];
    a0 += bflo(v0.x); a1 += bfhi(v0.x);
    a2 += bflo(v0.y); a3 += bfhi(v0.y);
    a4 += bflo(v0.z); a5 += bfhi(v0.z);
    a6 += bflo(v0.w); a7 += bfhi(v0.w);
  }
  if (e + (int)grp < e1) {  // tail 1..7 edges: group-masked
    uint c0 = cc[e + grp];
    uint4 v0 = X4[c0 * 8u + o8];
    a0 += bflo(v0.x); a1 += bfhi(v0.x);
    a2 += bflo(v0.y); a3 += bfhi(v0.y);
    a4 += bflo(v0.z); a5 += bfhi(v0.z);
    a6 += bflo(v0.w); a7 += bfhi(v0.w);
  }
  a0 += __shfl_xor(a0, 8);  a1 += __shfl_xor(a1, 8);
  a2 += __shfl_xor(a2, 8);  a3 += __shfl_xor(a3, 8);
  a4 += __shfl_xor(a4, 8);  a5 += __shfl_xor(a5, 8);
  a6 += __shfl_xor(a6, 8);  a7 += __shfl_xor(a7, 8);
  a0 += __shfl_xor(a0, 16); a1 += __shfl_xor(a1, 16);
  a2 += __shfl_xor(a2, 16); a3 += __shfl_xor(a3, 16);
  a4 += __shfl_xor(a4, 16); a5 += __shfl_xor(a5, 16);
  a6 += __shfl_xor(a6, 16); a7 += __shfl_xor(a7, 16);
  a0 += __shfl_xor(a0, 32); a1 += __shfl_xor(a1, 32);
  a2 += __shfl_xor(a2, 32); a3 += __shfl_xor(a3, 32);
  a4 += __shfl_xor(a4, 32); a5 += __shfl_xor(a5, 32);
  a6 += __shfl_xor(a6, 32); a7 += __shfl_xor(a7, 32);
  a0 = (a0 + bflo(s.x)) * di; a1 = (a1 + bfhi(s.x)) * di;
  a2 = (a2 + bflo(s.y)) * di; a3 = (a3 + bfhi(s.y)) * di;
  a4 = (a4 + bflo(s.z)) * di; a5 = (a5 + bfhi(s.z)) * di;
  a6 = (a6 + bflo(s.w)) * di; a7 = (a7 + bfhi(s.w)) * di;
  if (lane < 8) {
    float4 o0, o1;
    o0.x = a0; o0.y = a1; o0.z = a2; o0.w = a3;
    o1.x = a4; o1.y = a5; o1.z = a6; o1.w = a7;
    Y4[(uint)node * 16u + o8 * 2 + 0] = o0;
    Y4[(uint)node * 16u + o8 * 2 + 1] = o1;
  }
}

// ---------------- launch ----------------
// Pipeline (uses (PX)W == P(XW) and D^-1/2 factoring):
//   memset gcur; combo: binbuf bucket-sort (1024 blocks) + W01p/W2p packs
//   buckoff:  off/dinv/cc (CSR, LDS-staged bucket)
//   mgemm128: x0b = bf16(dinv ⊙ (feat@W01))    [MFMA]
//   prop128q: x1b = bf16(relu(dinv ⊙ gather(x0b)))
//   mgemm64:  t2b = bf16(dinv ⊙ (x1b @ W2))    [MFMA]
//   prop64q8: out = dinv ⊙ gather(t2b)          (fp32)

extern "C" void kernel_launch(void* const* d_in, const int* in_sizes, int n_in,
                              void* d_out, int out_size, void* d_ws, size_t ws_size,
                              hipStream_t stream) {
  const float* feat = (const float*)d_in[0];
  const int* ei = (const int*)d_in[1];  // int32 per harness contract
  const float* W0 = (const float*)d_in[2];
  const float* W1 = (const float*)d_in[3];
  const float* W2 = (const float*)d_in[4];
  float4* out = (float4*)d_out;

  char* ws = (char*)d_ws;
  unsigned short* x0b = (unsigned short*)ws; ws += (size_t)N_NODES * 128 * 2;  // 25.6 MB
  unsigned short* x1b = (unsigned short*)ws; ws += (size_t)N_NODES * 128 * 2;  // 25.6 MB
  unsigned short* t2b = (unsigned short*)ws; ws += (size_t)N_NODES * 64 * 2;   // 12.8 MB
  unsigned* binbuf = (unsigned*)ws;          ws += (size_t)NB * CAP * 4;       // 8.0 MB
  uint* cc = (uint*)ws;                      ws += (size_t)N_EDGES * 4;        // 6.4 MB
  float* dinv = (float*)ws;                  ws += (size_t)N_NODES * 4;
  int* off = (int*)ws;                       ws += (size_t)(N_NODES + 2) * 4;
  int* gcur = (int*)ws;                      ws += (size_t)NB * 4;
  unsigned short* W01p = (unsigned short*)ws; ws += 128 * 128 * 2;
  unsigned short* W2p = (unsigned short*)ws;  ws += 128 * 64 * 2;

  hipMemsetAsync(gcur, 0, (size_t)NB * 4, stream);
  combo_k<<<NBLK + 96, 256, 0, stream>>>(ei, gcur, binbuf, W0, W1, W2, W01p, W2p);
  buckoff_k<<<NB, 256, 0, stream>>>(binbuf, gcur, off, dinv, cc);
  mgemm128_k<<<(N_NODES + 63) / 64, 256, 0, stream>>>(feat, W01p, x0b, dinv);
  prop128q_k<true><<<(N_NODES + 3) / 4, 256, 0, stream>>>((const uint4*)x0b, (uint4*)x1b,
                                                          off, cc, dinv);
  mgemm64_k<<<(N_NODES + 63) / 64, 256, 0, stream>>>(x1b, W2p, t2b, dinv);
  prop64q8_k<<<(N_NODES + 3) / 4, 256, 0, stream>>>((const uint4*)t2b, out, off, cc, dinv);
}

// Round 17
// 182.315 us; speedup vs baseline: 1.1701x; 1.1701x over previous
//
#include <hip/hip_runtime.h>

#define N_NODES 100000
#define N_EDGES 1600000
#define NB 391            // ceil(N_NODES/256) row-buckets of 256 rows
#define NBLK 256          // blocks for binning pass
#define CHUNK 6250        // ceil(N_EDGES/NBLK); even, 8B-aligned chunk starts
#define CAP 5120          // per-bucket binbuf capacity (mean 4096, sigma 64)

typedef unsigned int uint;
typedef __attribute__((ext_vector_type(8))) short short8v;  // 8 bf16 (4 VGPRs)
typedef __attribute__((ext_vector_type(4))) float f32x4;

// ---------------- bf16 helpers ----------------

__device__ __forceinline__ uint bfrn(float x) {  // fp32 -> bf16 bits (RN)
  uint u = __float_as_uint(x);
  u += 0x7fffu + ((u >> 16) & 1u);
  return u >> 16;
}
__device__ __forceinline__ uint bfpack(float a, float b) {
  return bfrn(a) | (bfrn(b) << 16);
}
__device__ __forceinline__ float bflo(uint u) { return __uint_as_float(u << 16); }
__device__ __forceinline__ float bfhi(uint u) { return __uint_as_float(u & 0xffff0000u); }

// ---------------- kernel A: binning (blocks 0-255) + weight packs (256-351) -------
// gcur zero-init by hipMemsetAsync; reservation slot = i*CAP + atomicAdd(gcur[i],c).
// NBLK=256 is deliberate: larger grids fragment binbuf runs (<64B partial-line
// writes, 5x WRITE amplification) and multiply global-atomic contention (R16).
// Packed B-fragment index for element (k,f), NCT=FOUT/16:
//   ks=k>>5, j=k&7, lq=(k>>3)&3, lane=(lq<<4)|(f&15), ct=f>>4
//   idx = ((ks*NCT + ct)*64 + lane)*8 + j

__global__ __launch_bounds__(256) void combo_k(const int* __restrict__ ei,
                                               int* __restrict__ gcur,
                                               unsigned* __restrict__ binbuf,
                                               const float* __restrict__ W0,
                                               const float* __restrict__ W1,
                                               const float* __restrict__ W2,
                                               unsigned short* __restrict__ W01p,
                                               unsigned short* __restrict__ W2p) {
  int b = blockIdx.x;
  if (b < NBLK) {
    __shared__ int lh[NB];
    __shared__ int rstage[CHUNK];  // 25 KB: stage r to avoid global re-read
    for (int i = threadIdx.x; i < NB; i += 256) lh[i] = 0;
    __syncthreads();
    int ebeg = b * CHUNK;
    int n = min(CHUNK, N_EDGES - ebeg);  // == CHUNK (6250 even)
    const int2* ei2r = (const int2*)(ei + ebeg);
    for (int t = threadIdx.x; t < n / 2; t += 256) {  // int2: 2 edges per load
      int2 rr = ei2r[t];
      rstage[2 * t] = rr.x;
      rstage[2 * t + 1] = rr.y;
      atomicAdd(&lh[rr.x >> 8], 1);
      atomicAdd(&lh[rr.y >> 8], 1);
    }
    __syncthreads();
    for (int i = threadIdx.x; i < NB; i += 256) {
      int c = lh[i];
      lh[i] = c ? (i * CAP + atomicAdd(&gcur[i], c)) : 0;
    }
    __syncthreads();
    const int2* ei2c = (const int2*)(ei + N_EDGES + ebeg);
    for (int t = threadIdx.x; t < n / 2; t += 256) {
      int2 cc2 = ei2c[t];
      int r0 = rstage[2 * t], r1 = rstage[2 * t + 1];
      int p0 = atomicAdd(&lh[r0 >> 8], 1);
      binbuf[p0] = ((unsigned)(r0 & 255) << 24) | (unsigned)cc2.x;
      int p1 = atomicAdd(&lh[r1 >> 8], 1);
      binbuf[p1] = ((unsigned)(r1 & 255) << 24) | (unsigned)cc2.y;
    }
  } else if (b < NBLK + 64) {
    int g = (b - NBLK) * 256 + threadIdx.x;  // 16384: W01 = W0@W1
    int k = g >> 7, f = g & 127;
    float s = 0.f;
    for (int kk = 0; kk < 128; kk++) s = fmaf(W0[k * 128 + kk], W1[kk * 128 + f], s);
    int ks = k >> 5, j = k & 7, lq = (k >> 3) & 3;
    int lane = (lq << 4) | (f & 15), ct = f >> 4;
    W01p[((ks * 8 + ct) * 64 + lane) * 8 + j] = (unsigned short)bfrn(s);
  } else {
    int g = (b - NBLK - 64) * 256 + threadIdx.x;  // 8192: W2
    int k = g >> 6, f = g & 63;
    int ks = k >> 5, j = k & 7, lq = (k >> 3) & 3;
    int lane = (lq << 4) | (f & 15), ct = f >> 4;
    W2p[((ks * 4 + ct) * 64 + lane) * 8 + j] = (unsigned short)bfrn(W2[k * 64 + f]);
  }
}

// ---------------- kernel B: per-bucket CSR build; bucket edges staged in LDS ------

__global__ __launch_bounds__(256) void buckoff_k(const unsigned* __restrict__ binbuf,
                                                 const int* __restrict__ gcur,
                                                 int* __restrict__ off,
                                                 float* __restrict__ dinv,
                                                 uint* __restrict__ cc) {
  __shared__ unsigned est[CAP];  // 20 KB: this bucket's edges
  __shared__ int cnt[256];
  __shared__ int sc[256];
  __shared__ int sbase_s;
  int k = blockIdx.x, row0n = k << 8, tid = threadIdx.x;
  if (tid < 64) {  // sbase = sum_{j<k} count_j
    int s = 0;
    for (int j = tid; j < k; j += 64) s += gcur[j];
#pragma unroll
    for (int d = 32; d; d >>= 1) s += __shfl_xor(s, d);
    if (tid == 0) sbase_s = s;
  }
  cnt[tid] = 0;
  __syncthreads();
  int n = gcur[k];
  int sb = k * CAP;
  for (int t = tid; t < n; t += 256) {  // single global read of the bucket
    unsigned u = binbuf[sb + t];
    est[t] = u;
    atomicAdd(&cnt[u >> 24], 1);
  }
  __syncthreads();
  int v = cnt[tid];
  sc[tid] = v;
  __syncthreads();
  for (int d = 1; d < 256; d <<= 1) {
    int t = (tid >= d) ? sc[tid - d] : 0;
    __syncthreads();
    sc[tid] += t;
    __syncthreads();
  }
  int row = row0n + tid;
  int mystart = sbase_s + sc[tid] - v;
  if (row < N_NODES) {
    off[row] = mystart;
    dinv[row] = rsqrtf((float)v + 1.0f);  // +1 = self-loop
  }
  if (k == NB - 1 && tid == 0) off[N_NODES] = N_EDGES;
  __syncthreads();
  cnt[tid] = mystart;  // reuse as placement cursor
  __syncthreads();
  for (int t = tid; t < n; t += 256) {
    unsigned u = est[t];
    int slot = atomicAdd(&cnt[u >> 24], 1);
    cc[slot] = u & 0xFFFFFFu;
  }
}

// ---------------- MFMA GEMM 128->128: x0b = bf16(dinv ⊙ (feat @ W01)) -------------

__global__ __launch_bounds__(256) void mgemm128_k(const float* __restrict__ feat,
                                                  const unsigned short* __restrict__ Wp,
                                                  unsigned short* __restrict__ Cb,
                                                  const float* __restrict__ dinv) {
  __shared__ uint4 Al4[64 * 16];    // 16 KB A tile (swizzled bf16)
  __shared__ uint4 Wl4[128 * 16];   // 32 KB packed W01 fragments
  char* Al = (char*)Al4;
  int tid = threadIdx.x;
  int row0 = blockIdx.x * 64;
  for (int i = tid; i < 128 * 16; i += 256) Wl4[i] = ((const uint4*)Wp)[i];
  const float4* Af = (const float4*)feat;
  for (int i = tid; i < 64 * 32; i += 256) {
    int r = i >> 5, c4 = i & 31;
    int gr = row0 + r;
    float4 vv = make_float4(0.f, 0.f, 0.f, 0.f);
    if (gr < N_NODES) vv = Af[(uint)gr * 32u + c4];
    uint2 p;
    p.x = bfpack(vv.x, vv.y);
    p.y = bfpack(vv.z, vv.w);
    int byte = (r * 256 + c4 * 8) ^ ((r & 7) << 4);
    *(uint2*)(Al + byte) = p;
  }
  __syncthreads();
  int lane = tid & 63, w = tid >> 6;
  f32x4 acc[8];
#pragma unroll
  for (int ct = 0; ct < 8; ct++) acc[ct] = (f32x4){0.f, 0.f, 0.f, 0.f};
  int arow = w * 16 + (lane & 15);
#pragma unroll
  for (int ks = 0; ks < 4; ks++) {
    int abyte = (arow * 256 + ks * 64 + (lane >> 4) * 16) ^ ((arow & 7) << 4);
    short8v a = *(const short8v*)(Al + abyte);
#pragma unroll
    for (int ct = 0; ct < 8; ct++) {
      short8v bb = *(const short8v*)((const char*)Wl4 + ((ks * 8 + ct) * 64 + lane) * 16);
      acc[ct] = __builtin_amdgcn_mfma_f32_16x16x32_bf16(a, bb, acc[ct], 0, 0, 0);
    }
  }
#pragma unroll
  for (int j = 0; j < 4; j++) {
    int grow = row0 + w * 16 + ((lane >> 4) << 2) + j;
    if (grow < N_NODES) {
      float scale = dinv[grow];
#pragma unroll
      for (int ct = 0; ct < 8; ct++) {
        Cb[(uint)grow * 128u + ct * 16 + (lane & 15)] =
            (unsigned short)bfrn(acc[ct][j] * scale);
      }
    }
  }
}

// ---------------- prop, 128 bf16 feats, 4 edges/wave-load, 16-edge deep loop ------
// X pre-scaled (x' = dinv*x). grp = lane>>4 picks edge; o16 = lane&15 picks 8 feats.
// PURE gather kernel: no LDS, no block sync — must stay maximally occupant (R10/R14).

template <bool RELU>
__global__ __launch_bounds__(256) void prop128q_k(const uint4* __restrict__ X4,  // bf16x8
                                                  uint4* __restrict__ Yb4,       // bf16x8
                                                  const int* __restrict__ off,
                                                  const uint* __restrict__ cc,
                                                  const float* __restrict__ dinv) {
  int node = blockIdx.x * 4 + (threadIdx.x >> 6);
  if (node >= N_NODES) return;
  uint lane = threadIdx.x & 63u;
  uint grp = lane >> 4, o16 = lane & 15u;
  float di = dinv[node];
  uint4 s = X4[(uint)node * 16u + o16];
  float a0 = 0.f, a1 = 0.f, a2 = 0.f, a3 = 0.f, a4 = 0.f, a5 = 0.f, a6 = 0.f, a7 = 0.f;
  int e = off[node], e1 = off[node + 1];
  for (; e + 15 < e1; e += 16) {  // 4 quads = 16 edges, 4 row-loads in flight
    uint c0 = cc[e + grp], c1 = cc[e + 4 + grp], c2 = cc[e + 8 + grp], c3 = cc[e + 12 + grp];
    uint4 v0 = X4[c0 * 16u + o16];
    uint4 v1 = X4[c1 * 16u + o16];
    uint4 v2 = X4[c2 * 16u + o16];
    uint4 v3 = X4[c3 * 16u + o16];
    a0 += bflo(v0.x) + bflo(v1.x) + bflo(v2.x) + bflo(v3.x);
    a1 += bfhi(v0.x) + bfhi(v1.x) + bfhi(v2.x) + bfhi(v3.x);
    a2 += bflo(v0.y) + bflo(v1.y) + bflo(v2.y) + bflo(v3.y);
    a3 += bfhi(v0.y) + bfhi(v1.y) + bfhi(v2.y) + bfhi(v3.y);
    a4 += bflo(v0.z) + bflo(v1.z) + bflo(v2.z) + bflo(v3.z);
    a5 += bfhi(v0.z) + bfhi(v1.z) + bfhi(v2.z) + bfhi(v3.z);
    a6 += bflo(v0.w) + bflo(v1.w) + bflo(v2.w) + bflo(v3.w);
    a7 += bfhi(v0.w) + bfhi(v1.w) + bfhi(v2.w) + bfhi(v3.w);
  }
  for (; e + 7 < e1; e += 8) {  // 2 quads
    uint c0 = cc[e + grp], c1 = cc[e + 4 + grp];
    uint4 v0 = X4[c0 * 16u + o16];
    uint4 v1 = X4[c1 * 16u + o16];
    a0 += bflo(v0.x) + bflo(v1.x);
    a1 += bfhi(v0.x) + bfhi(v1.x);
    a2 += bflo(v0.y) + bflo(v1.y);
    a3 += bfhi(v0.y) + bfhi(v1.y);
    a4 += bflo(v0.z) + bflo(v1.z);
    a5 += bfhi(v0.z) + bfhi(v1.z);
    a6 += bflo(v0.w) + bflo(v1.w);
    a7 += bfhi(v0.w) + bfhi(v1.w);
  }
  for (; e + 3 < e1; e += 4) {  // one quad
    uint c0 = cc[e + grp];
    uint4 v0 = X4[c0 * 16u + o16];
    a0 += bflo(v0.x); a1 += bfhi(v0.x);
    a2 += bflo(v0.y); a3 += bfhi(v0.y);
    a4 += bflo(v0.z); a5 += bfhi(v0.z);
    a6 += bflo(v0.w); a7 += bfhi(v0.w);
  }
  if (e + (int)grp < e1) {  // tail 1..3 edges: group-masked
    uint c0 = cc[e + grp];
    uint4 v0 = X4[c0 * 16u + o16];
    a0 += bflo(v0.x); a1 += bfhi(v0.x);
    a2 += bflo(v0.y); a3 += bfhi(v0.y);
    a4 += bflo(v0.z); a5 += bfhi(v0.z);
    a6 += bflo(v0.w); a7 += bfhi(v0.w);
  }
  a0 += __shfl_xor(a0, 16); a1 += __shfl_xor(a1, 16);
  a2 += __shfl_xor(a2, 16); a3 += __shfl_xor(a3, 16);
  a4 += __shfl_xor(a4, 16); a5 += __shfl_xor(a5, 16);
  a6 += __shfl_xor(a6, 16); a7 += __shfl_xor(a7, 16);
  a0 += __shfl_xor(a0, 32); a1 += __shfl_xor(a1, 32);
  a2 += __shfl_xor(a2, 32); a3 += __shfl_xor(a3, 32);
  a4 += __shfl_xor(a4, 32); a5 += __shfl_xor(a5, 32);
  a6 += __shfl_xor(a6, 32); a7 += __shfl_xor(a7, 32);
  a0 = (a0 + bflo(s.x)) * di; a1 = (a1 + bfhi(s.x)) * di;
  a2 = (a2 + bflo(s.y)) * di; a3 = (a3 + bfhi(s.y)) * di;
  a4 = (a4 + bflo(s.z)) * di; a5 = (a5 + bfhi(s.z)) * di;
  a6 = (a6 + bflo(s.w)) * di; a7 = (a7 + bfhi(s.w)) * di;
  if (RELU) {
    a0 = fmaxf(a0, 0.f); a1 = fmaxf(a1, 0.f); a2 = fmaxf(a2, 0.f); a3 = fmaxf(a3, 0.f);
    a4 = fmaxf(a4, 0.f); a5 = fmaxf(a5, 0.f); a6 = fmaxf(a6, 0.f); a7 = fmaxf(a7, 0.f);
  }
  if (lane < 16) {
    uint4 p;
    p.x = bfpack(a0, a1);
    p.y = bfpack(a2, a3);
    p.z = bfpack(a4, a5);
    p.w = bfpack(a6, a7);
    Yb4[(uint)node * 16u + o16] = p;
  }
}

// ---------------- MFMA GEMM: t2b[64 x 64] = x1b[64 x 128] @ W2, dinv epilogue -----

__global__ __launch_bounds__(256) void mgemm64_k(const unsigned short* __restrict__ Ab16,
                                                 const unsigned short* __restrict__ Wp,
                                                 unsigned short* __restrict__ Cb,
                                                 const float* __restrict__ dinv) {
  __shared__ uint4 Al4[64 * 16];  // 16 KB: 64 rows x 128 bf16 (swizzled)
  __shared__ uint4 Wl4[64 * 16];  // 16 KB packed W2 fragments
  char* Al = (char*)Al4;
  int tid = threadIdx.x;
  int row0 = blockIdx.x * 64;
  for (int i = tid; i < 64 * 16; i += 256) Wl4[i] = ((const uint4*)Wp)[i];
  const uint4* Ab = (const uint4*)Ab16;
  for (int i = tid; i < 64 * 16; i += 256) {
    int r = i >> 4, c8 = i & 15;
    int gr = row0 + r;
    uint4 v = make_uint4(0, 0, 0, 0);
    if (gr < N_NODES) v = Ab[(uint)gr * 16u + c8];
    int byte = (r * 256 + c8 * 16) ^ ((r & 7) << 4);
    *(uint4*)(Al + byte) = v;
  }
  __syncthreads();
  int lane = tid & 63, w = tid >> 6;
  f32x4 acc[4];
#pragma unroll
  for (int ct = 0; ct < 4; ct++) acc[ct] = (f32x4){0.f, 0.f, 0.f, 0.f};
  int arow = w * 16 + (lane & 15);
#pragma unroll
  for (int ks = 0; ks < 4; ks++) {
    int abyte = (arow * 256 + ks * 64 + (lane >> 4) * 16) ^ ((arow & 7) << 4);
    short8v a = *(const short8v*)(Al + abyte);
#pragma unroll
    for (int ct = 0; ct < 4; ct++) {
      short8v bb = *(const short8v*)((const char*)Wl4 + ((ks * 4 + ct) * 64 + lane) * 16);
      acc[ct] = __builtin_amdgcn_mfma_f32_16x16x32_bf16(a, bb, acc[ct], 0, 0, 0);
    }
  }
#pragma unroll
  for (int j = 0; j < 4; j++) {
    int grow = row0 + w * 16 + ((lane >> 4) << 2) + j;
    if (grow < N_NODES) {
      float scale = dinv[grow];
#pragma unroll
      for (int ct = 0; ct < 4; ct++) {
        Cb[(uint)grow * 64u + ct * 16 + (lane & 15)] =
            (unsigned short)bfrn(acc[ct][j] * scale);
      }
    }
  }
}

// ---------------- prop, 64 bf16 feats, 8 edges/wave-load (8 lanes x uint4) --------
// Row = 128 B = 8 lanes x 16 B. grp = lane>>3 (8 edges); o8 = lane&7 (8 feats).

__global__ __launch_bounds__(256) void prop64q8_k(const uint4* __restrict__ X4,  // bf16x8
                                                  float4* __restrict__ Y4,
                                                  const int* __restrict__ off,
                                                  const uint* __restrict__ cc,
                                                  const float* __restrict__ dinv) {
  int node = blockIdx.x * 4 + (threadIdx.x >> 6);
  if (node >= N_NODES) return;
  uint lane = threadIdx.x & 63u;
  uint grp = lane >> 3, o8 = lane & 7u;
  float di = dinv[node];
  uint4 s = X4[(uint)node * 8u + o8];
  float a0 = 0.f, a1 = 0.f, a2 = 0.f, a3 = 0.f, a4 = 0.f, a5 = 0.f, a6 = 0.f, a7 = 0.f;
  int e = off[node], e1 = off[node + 1];
  for (; e + 15 < e1; e += 16) {  // 2 x 8 edges, 2 row-loads in flight
    uint c0 = cc[e + grp], c1 = cc[e + 8 + grp];
    uint4 v0 = X4[c0 * 8u + o8];
    uint4 v1 = X4[c1 * 8u + o8];
    a0 += bflo(v0.x) + bflo(v1.x);
    a1 += bfhi(v0.x) + bfhi(v1.x);
    a2 += bflo(v0.y) + bflo(v1.y);
    a3 += bfhi(v0.y) + bfhi(v1.y);
    a4 += bflo(v0.z) + bflo(v1.z);
    a5 += bfhi(v0.z) + bfhi(v1.z);
    a6 += bflo(v0.w) + bflo(v1.w);
    a7 += bfhi(v0.w) + bfhi(v1.w);
  }
  for (; e + 7 < e1; e += 8) {  // 8 edges
    uint c0 = cc[e + grp];
    uint4 v0 = X4[c0 * 8u + o8];
    a0 += bflo(v0.x); a1 += bfhi(v0.x);
    a2 += bflo(v0.y); a3 += bfhi(v0.y);
    a4 += bflo(v0.z); a5 += bfhi(v0.z);
    a6 += bflo(v0.w); a7 += bfhi(v0.w);
  }
  if (e + (int)grp < e1) {  // tail 1..7 edges: group-masked
    uint c0 = cc[e + grp];
    uint4 v0 = X4[c0 * 8u + o8];
    a0 += bflo(v0.x); a1 += bfhi(v0.x);
    a2 += bflo(v0.y); a3 += bfhi(v0.y);
    a4 += bflo(v0.z); a5 += bfhi(v0.z);
    a6 += bflo(v0.w); a7 += bfhi(v0.w);
  }
  a0 += __shfl_xor(a0, 8);  a1 += __shfl_xor(a1, 8);
  a2 += __shfl_xor(a2, 8);  a3 += __shfl_xor(a3, 8);
  a4 += __shfl_xor(a4, 8);  a5 += __shfl_xor(a5, 8);
  a6 += __shfl_xor(a6, 8);  a7 += __shfl_xor(a7, 8);
  a0 += __shfl_xor(a0, 16); a1 += __shfl_xor(a1, 16);
  a2 += __shfl_xor(a2, 16); a3 += __shfl_xor(a3, 16);
  a4 += __shfl_xor(a4, 16); a5 += __shfl_xor(a5, 16);
  a6 += __shfl_xor(a6, 16); a7 += __shfl_xor(a7, 16);
  a0 += __shfl_xor(a0, 32); a1 += __shfl_xor(a1, 32);
  a2 += __shfl_xor(a2, 32); a3 += __shfl_xor(a3, 32);
  a4 += __shfl_xor(a4, 32); a5 += __shfl_xor(a5, 32);
  a6 += __shfl_xor(a6, 32); a7 += __shfl_xor(a7, 32);
  a0 = (a0 + bflo(s.x)) * di; a1 = (a1 + bfhi(s.x)) * di;
  a2 = (a2 + bflo(s.y)) * di; a3 = (a3 + bfhi(s.y)) * di;
  a4 = (a4 + bflo(s.z)) * di; a5 = (a5 + bfhi(s.z)) * di;
  a6 = (a6 + bflo(s.w)) * di; a7 = (a7 + bfhi(s.w)) * di;
  if (lane < 8) {
    float4 o0, o1;
    o0.x = a0; o0.y = a1; o0.z = a2; o0.w = a3;
    o1.x = a4; o1.y = a5; o1.z = a6; o1.w = a7;
    Y4[(uint)node * 16u + o8 * 2 + 0] = o0;
    Y4[(uint)node * 16u + o8 * 2 + 1] = o1;
  }
}

// ---------------- launch ----------------
// Pipeline (uses (PX)W == P(XW) and D^-1/2 factoring):
//   memset gcur; combo: binbuf bucket-sort (256 blocks) + W01p/W2p packs
//   buckoff:  off/dinv/cc (CSR, LDS-staged bucket)
//   mgemm128: x0b = bf16(dinv ⊙ (feat@W01))    [MFMA]
//   prop128q: x1b = bf16(relu(dinv ⊙ gather(x0b)))
//   mgemm64:  t2b = bf16(dinv ⊙ (x1b @ W2))    [MFMA]
//   prop64q8: out = dinv ⊙ gather(t2b)          (fp32)

extern "C" void kernel_launch(void* const* d_in, const int* in_sizes, int n_in,
                              void* d_out, int out_size, void* d_ws, size_t ws_size,
                              hipStream_t stream) {
  const float* feat = (const float*)d_in[0];
  const int* ei = (const int*)d_in[1];  // int32 per harness contract
  const float* W0 = (const float*)d_in[2];
  const float* W1 = (const float*)d_in[3];
  const float* W2 = (const float*)d_in[4];
  float4* out = (float4*)d_out;

  char* ws = (char*)d_ws;
  unsigned short* x0b = (unsigned short*)ws; ws += (size_t)N_NODES * 128 * 2;  // 25.6 MB
  unsigned short* x1b = (unsigned short*)ws; ws += (size_t)N_NODES * 128 * 2;  // 25.6 MB
  unsigned short* t2b = (unsigned short*)ws; ws += (size_t)N_NODES * 64 * 2;   // 12.8 MB
  unsigned* binbuf = (unsigned*)ws;          ws += (size_t)NB * CAP * 4;       // 8.0 MB
  uint* cc = (uint*)ws;                      ws += (size_t)N_EDGES * 4;        // 6.4 MB
  float* dinv = (float*)ws;                  ws += (size_t)N_NODES * 4;
  int* off = (int*)ws;                       ws += (size_t)(N_NODES + 2) * 4;
  int* gcur = (int*)ws;                      ws += (size_t)NB * 4;
  unsigned short* W01p = (unsigned short*)ws; ws += 128 * 128 * 2;
  unsigned short* W2p = (unsigned short*)ws;  ws += 128 * 64 * 2;

  hipMemsetAsync(gcur, 0, (size_t)NB * 4, stream);
  combo_k<<<NBLK + 96, 256, 0, stream>>>(ei, gcur, binbuf, W0, W1, W2, W01p, W2p);
  buckoff_k<<<NB, 256, 0, stream>>>(binbuf, gcur, off, dinv, cc);
  mgemm128_k<<<(N_NODES + 63) / 64, 256, 0, stream>>>(feat, W01p, x0b, dinv);
  prop128q_k<true><<<(N_NODES + 3) / 4, 256, 0, stream>>>((const uint4*)x0b, (uint4*)x1b,
                                                          off, cc, dinv);
  mgemm64_k<<<(N_NODES + 63) / 64, 256, 0, stream>>>(x1b, W2p, t2b, dinv);
  prop64q8_k<<<(N_NODES + 3) / 4, 256, 0, stream>>>((const uint4*)t2b, out, off, cc, dinv);
}

// Round 18
// 181.694 us; speedup vs baseline: 1.1741x; 1.0034x over previous
//
#include <hip/hip_runtime.h>

#define N_NODES 100000
#define N_EDGES 1600000
#define NB 391            // ceil(N_NODES/256) row-buckets of 256 rows
#define NBLK 256          // blocks for binning pass (DO NOT raise: R16 — run
                          // fragmentation + atomic contention; raise WAVES instead)
#define CHUNK 6250        // ceil(N_EDGES/NBLK); even, 8B-aligned chunk starts
#define CAP 5120          // per-bucket binbuf capacity (mean 4096, sigma 64)

typedef unsigned int uint;
typedef __attribute__((ext_vector_type(8))) short short8v;  // 8 bf16 (4 VGPRs)
typedef __attribute__((ext_vector_type(4))) float f32x4;

// ---------------- bf16 helpers ----------------

__device__ __forceinline__ uint bfrn(float x) {  // fp32 -> bf16 bits (RN)
  uint u = __float_as_uint(x);
  u += 0x7fffu + ((u >> 16) & 1u);
  return u >> 16;
}
__device__ __forceinline__ uint bfpack(float a, float b) {
  return bfrn(a) | (bfrn(b) << 16);
}
__device__ __forceinline__ float bflo(uint u) { return __uint_as_float(u << 16); }
__device__ __forceinline__ float bfhi(uint u) { return __uint_as_float(u & 0xffff0000u); }

// ---------------- kernel A: binning (blocks 0-255, 1024 thr) + weight packs -------
// 1024 threads/block = 16 waves/CU (was 4) to hide global-load + LDS-atomic
// latency; chunk/run structure identical to the 256-thread version (R16 lesson:
// fragmenting runs is the failure mode, not TLP).
// gcur zero-init by hipMemsetAsync; reservation slot = i*CAP + atomicAdd(gcur[i],c).
// Packed B-fragment index for element (k,f), NCT=FOUT/16:
//   ks=k>>5, j=k&7, lq=(k>>3)&3, lane=(lq<<4)|(f&15), ct=f>>4
//   idx = ((ks*NCT + ct)*64 + lane)*8 + j

__global__ __launch_bounds__(1024) void combo_k(const int* __restrict__ ei,
                                                int* __restrict__ gcur,
                                                unsigned* __restrict__ binbuf,
                                                const float* __restrict__ W0,
                                                const float* __restrict__ W1,
                                                const float* __restrict__ W2,
                                                unsigned short* __restrict__ W01p,
                                                unsigned short* __restrict__ W2p) {
  int b = blockIdx.x;
  int tid = threadIdx.x;
  if (b < NBLK) {
    __shared__ int lh[NB];
    __shared__ int rstage[CHUNK];  // 25 KB: stage r to avoid global re-read
    for (int i = tid; i < NB; i += 1024) lh[i] = 0;
    __syncthreads();
    int ebeg = b * CHUNK;
    int n = min(CHUNK, N_EDGES - ebeg);  // == CHUNK (6250 even)
    const int2* ei2r = (const int2*)(ei + ebeg);
    for (int t = tid; t < n / 2; t += 1024) {  // int2: 2 edges per load
      int2 rr = ei2r[t];
      rstage[2 * t] = rr.x;
      rstage[2 * t + 1] = rr.y;
      atomicAdd(&lh[rr.x >> 8], 1);
      atomicAdd(&lh[rr.y >> 8], 1);
    }
    __syncthreads();
    for (int i = tid; i < NB; i += 1024) {
      int c = lh[i];
      lh[i] = c ? (i * CAP + atomicAdd(&gcur[i], c)) : 0;
    }
    __syncthreads();
    const int2* ei2c = (const int2*)(ei + N_EDGES + ebeg);
    for (int t = tid; t < n / 2; t += 1024) {
      int2 cc2 = ei2c[t];
      int r0 = rstage[2 * t], r1 = rstage[2 * t + 1];
      int p0 = atomicAdd(&lh[r0 >> 8], 1);
      binbuf[p0] = ((unsigned)(r0 & 255) << 24) | (unsigned)cc2.x;
      int p1 = atomicAdd(&lh[r1 >> 8], 1);
      binbuf[p1] = ((unsigned)(r1 & 255) << 24) | (unsigned)cc2.y;
    }
  } else if (b < NBLK + 16) {
    int g = (b - NBLK) * 1024 + tid;  // 16384: W01 = W0@W1
    int k = g >> 7, f = g & 127;
    float s = 0.f;
    for (int kk = 0; kk < 128; kk++) s = fmaf(W0[k * 128 + kk], W1[kk * 128 + f], s);
    int ks = k >> 5, j = k & 7, lq = (k >> 3) & 3;
    int lane = (lq << 4) | (f & 15), ct = f >> 4;
    W01p[((ks * 8 + ct) * 64 + lane) * 8 + j] = (unsigned short)bfrn(s);
  } else {
    int g = (b - NBLK - 16) * 1024 + tid;  // 8192: W2
    int k = g >> 6, f = g & 63;
    int ks = k >> 5, j = k & 7, lq = (k >> 3) & 3;
    int lane = (lq << 4) | (f & 15), ct = f >> 4;
    W2p[((ks * 4 + ct) * 64 + lane) * 8 + j] = (unsigned short)bfrn(W2[k * 64 + f]);
  }
}

// ---------------- kernel B: per-bucket CSR build (1024 thr); LDS-staged bucket ----

__global__ __launch_bounds__(1024) void buckoff_k(const unsigned* __restrict__ binbuf,
                                                  const int* __restrict__ gcur,
                                                  int* __restrict__ off,
                                                  float* __restrict__ dinv,
                                                  uint* __restrict__ cc) {
  __shared__ unsigned est[CAP];  // 20 KB: this bucket's edges
  __shared__ int cnt[256];
  __shared__ int sc[256];
  __shared__ int sbase_s;
  int k = blockIdx.x, row0n = k << 8, tid = threadIdx.x;
  if (tid < 64) {  // sbase = sum_{j<k} count_j (wave 0)
    int s = 0;
    for (int j = tid; j < k; j += 64) s += gcur[j];
#pragma unroll
    for (int d = 32; d; d >>= 1) s += __shfl_xor(s, d);
    if (tid == 0) sbase_s = s;
  }
  if (tid < 256) cnt[tid] = 0;
  __syncthreads();
  int n = gcur[k];
  int sb = k * CAP;
  for (int t = tid; t < n; t += 1024) {  // single global read of the bucket
    unsigned u = binbuf[sb + t];
    est[t] = u;
    atomicAdd(&cnt[u >> 24], 1);
  }
  __syncthreads();
  int v = 0;
  if (tid < 256) {
    v = cnt[tid];
    sc[tid] = v;
  }
  __syncthreads();
  for (int d = 1; d < 256; d <<= 1) {
    int t = 0;
    if (tid < 256 && tid >= d) t = sc[tid - d];
    __syncthreads();
    if (tid < 256) sc[tid] += t;
    __syncthreads();
  }
  if (tid < 256) {
    int row = row0n + tid;
    int mystart = sbase_s + sc[tid] - v;
    if (row < N_NODES) {
      off[row] = mystart;
      dinv[row] = rsqrtf((float)v + 1.0f);  // +1 = self-loop
    }
    cnt[tid] = mystart;  // reuse as placement cursor
  }
  if (k == NB - 1 && tid == 0) off[N_NODES] = N_EDGES;
  __syncthreads();
  for (int t = tid; t < n; t += 1024) {
    unsigned u = est[t];
    int slot = atomicAdd(&cnt[u >> 24], 1);
    cc[slot] = u & 0xFFFFFFu;
  }
}

// ---------------- MFMA GEMM 128->128: x0b = bf16(dinv ⊙ (feat @ W01)) -------------

__global__ __launch_bounds__(256) void mgemm128_k(const float* __restrict__ feat,
                                                  const unsigned short* __restrict__ Wp,
                                                  unsigned short* __restrict__ Cb,
                                                  const float* __restrict__ dinv) {
  __shared__ uint4 Al4[64 * 16];    // 16 KB A tile (swizzled bf16)
  __shared__ uint4 Wl4[128 * 16];   // 32 KB packed W01 fragments
  char* Al = (char*)Al4;
  int tid = threadIdx.x;
  int row0 = blockIdx.x * 64;
  for (int i = tid; i < 128 * 16; i += 256) Wl4[i] = ((const uint4*)Wp)[i];
  const float4* Af = (const float4*)feat;
  for (int i = tid; i < 64 * 32; i += 256) {
    int r = i >> 5, c4 = i & 31;
    int gr = row0 + r;
    float4 vv = make_float4(0.f, 0.f, 0.f, 0.f);
    if (gr < N_NODES) vv = Af[(uint)gr * 32u + c4];
    uint2 p;
    p.x = bfpack(vv.x, vv.y);
    p.y = bfpack(vv.z, vv.w);
    int byte = (r * 256 + c4 * 8) ^ ((r & 7) << 4);
    *(uint2*)(Al + byte) = p;
  }
  __syncthreads();
  int lane = tid & 63, w = tid >> 6;
  f32x4 acc[8];
#pragma unroll
  for (int ct = 0; ct < 8; ct++) acc[ct] = (f32x4){0.f, 0.f, 0.f, 0.f};
  int arow = w * 16 + (lane & 15);
#pragma unroll
  for (int ks = 0; ks < 4; ks++) {
    int abyte = (arow * 256 + ks * 64 + (lane >> 4) * 16) ^ ((arow & 7) << 4);
    short8v a = *(const short8v*)(Al + abyte);
#pragma unroll
    for (int ct = 0; ct < 8; ct++) {
      short8v bb = *(const short8v*)((const char*)Wl4 + ((ks * 8 + ct) * 64 + lane) * 16);
      acc[ct] = __builtin_amdgcn_mfma_f32_16x16x32_bf16(a, bb, acc[ct], 0, 0, 0);
    }
  }
#pragma unroll
  for (int j = 0; j < 4; j++) {
    int grow = row0 + w * 16 + ((lane >> 4) << 2) + j;
    if (grow < N_NODES) {
      float scale = dinv[grow];
#pragma unroll
      for (int ct = 0; ct < 8; ct++) {
        Cb[(uint)grow * 128u + ct * 16 + (lane & 15)] =
            (unsigned short)bfrn(acc[ct][j] * scale);
      }
    }
  }
}

// ---------------- prop, 128 bf16 feats, 4 edges/wave-load, 16-edge deep loop ------
// X pre-scaled (x' = dinv*x). grp = lane>>4 picks edge; o16 = lane&15 picks 8 feats.
// PURE gather kernel: no LDS, no block sync — must stay maximally occupant (R10/R14).

template <bool RELU>
__global__ __launch_bounds__(256) void prop128q_k(const uint4* __restrict__ X4,  // bf16x8
                                                  uint4* __restrict__ Yb4,       // bf16x8
                                                  const int* __restrict__ off,
                                                  const uint* __restrict__ cc,
                                                  const float* __restrict__ dinv) {
  int node = blockIdx.x * 4 + (threadIdx.x >> 6);
  if (node >= N_NODES) return;
  uint lane = threadIdx.x & 63u;
  uint grp = lane >> 4, o16 = lane & 15u;
  float di = dinv[node];
  uint4 s = X4[(uint)node * 16u + o16];
  float a0 = 0.f, a1 = 0.f, a2 = 0.f, a3 = 0.f, a4 = 0.f, a5 = 0.f, a6 = 0.f, a7 = 0.f;
  int e = off[node], e1 = off[node + 1];
  for (; e + 15 < e1; e += 16) {  // 4 quads = 16 edges, 4 row-loads in flight
    uint c0 = cc[e + grp], c1 = cc[e + 4 + grp], c2 = cc[e + 8 + grp], c3 = cc[e + 12 + grp];
    uint4 v0 = X4[c0 * 16u + o16];
    uint4 v1 = X4[c1 * 16u + o16];
    uint4 v2 = X4[c2 * 16u + o16];
    uint4 v3 = X4[c3 * 16u + o16];
    a0 += bflo(v0.x) + bflo(v1.x) + bflo(v2.x) + bflo(v3.x);
    a1 += bfhi(v0.x) + bfhi(v1.x) + bfhi(v2.x) + bfhi(v3.x);
    a2 += bflo(v0.y) + bflo(v1.y) + bflo(v2.y) + bflo(v3.y);
    a3 += bfhi(v0.y) + bfhi(v1.y) + bfhi(v2.y) + bfhi(v3.y);
    a4 += bflo(v0.z) + bflo(v1.z) + bflo(v2.z) + bflo(v3.z);
    a5 += bfhi(v0.z) + bfhi(v1.z) + bfhi(v2.z) + bfhi(v3.z);
    a6 += bflo(v0.w) + bflo(v1.w) + bflo(v2.w) + bflo(v3.w);
    a7 += bfhi(v0.w) + bfhi(v1.w) + bfhi(v2.w) + bfhi(v3.w);
  }
  for (; e + 7 < e1; e += 8) {  // 2 quads
    uint c0 = cc[e + grp], c1 = cc[e + 4 + grp];
    uint4 v0 = X4[c0 * 16u + o16];
    uint4 v1 = X4[c1 * 16u + o16];
    a0 += bflo(v0.x) + bflo(v1.x);
    a1 += bfhi(v0.x) + bfhi(v1.x);
    a2 += bflo(v0.y) + bflo(v1.y);
    a3 += bfhi(v0.y) + bfhi(v1.y);
    a4 += bflo(v0.z) + bflo(v1.z);
    a5 += bfhi(v0.z) + bfhi(v1.z);
    a6 += bflo(v0.w) + bflo(v1.w);
    a7 += bfhi(v0.w) + bfhi(v1.w);
  }
  for (; e + 3 < e1; e += 4) {  // one quad
    uint c0 = cc[e + grp];
    uint4 v0 = X4[c0 * 16u + o16];
    a0 += bflo(v0.x); a1 += bfhi(v0.x);
    a2 += bflo(v0.y); a3 += bfhi(v0.y);
    a4 += bflo(v0.z); a5 += bfhi(v0.z);
    a6 += bflo(v0.w); a7 += bfhi(v0.w);
  }
  if (e + (int)grp < e1) {  // tail 1..3 edges: group-masked
    uint c0 = cc[e + grp];
    uint4 v0 = X4[c0 * 16u + o16];
    a0 += bflo(v0.x); a1 += bfhi(v0.x);
    a2 += bflo(v0.y); a3 += bfhi(v0.y);
    a4 += bflo(v0.z); a5 += bfhi(v0.z);
    a6 += bflo(v0.w); a7 += bfhi(v0.w);
  }
  a0 += __shfl_xor(a0, 16); a1 += __shfl_xor(a1, 16);
  a2 += __shfl_xor(a2, 16); a3 += __shfl_xor(a3, 16);
  a4 += __shfl_xor(a4, 16); a5 += __shfl_xor(a5, 16);
  a6 += __shfl_xor(a6, 16); a7 += __shfl_xor(a7, 16);
  a0 += __shfl_xor(a0, 32); a1 += __shfl_xor(a1, 32);
  a2 += __shfl_xor(a2, 32); a3 += __shfl_xor(a3, 32);
  a4 += __shfl_xor(a4, 32); a5 += __shfl_xor(a5, 32);
  a6 += __shfl_xor(a6, 32); a7 += __shfl_xor(a7, 32);
  a0 = (a0 + bflo(s.x)) * di; a1 = (a1 + bfhi(s.x)) * di;
  a2 = (a2 + bflo(s.y)) * di; a3 = (a3 + bfhi(s.y)) * di;
  a4 = (a4 + bflo(s.z)) * di; a5 = (a5 + bfhi(s.z)) * di;
  a6 = (a6 + bflo(s.w)) * di; a7 = (a7 + bfhi(s.w)) * di;
  if (RELU) {
    a0 = fmaxf(a0, 0.f); a1 = fmaxf(a1, 0.f); a2 = fmaxf(a2, 0.f); a3 = fmaxf(a3, 0.f);
    a4 = fmaxf(a4, 0.f); a5 = fmaxf(a5, 0.f); a6 = fmaxf(a6, 0.f); a7 = fmaxf(a7, 0.f);
  }
  if (lane < 16) {
    uint4 p;
    p.x = bfpack(a0, a1);
    p.y = bfpack(a2, a3);
    p.z = bfpack(a4, a5);
    p.w = bfpack(a6, a7);
    Yb4[(uint)node * 16u + o16] = p;
  }
}

// ---------------- MFMA GEMM: t2b[64 x 64] = x1b[64 x 128] @ W2, dinv epilogue -----

__global__ __launch_bounds__(256) void mgemm64_k(const unsigned short* __restrict__ Ab16,
                                                 const unsigned short* __restrict__ Wp,
                                                 unsigned short* __restrict__ Cb,
                                                 const float* __restrict__ dinv) {
  __shared__ uint4 Al4[64 * 16];  // 16 KB: 64 rows x 128 bf16 (swizzled)
  __shared__ uint4 Wl4[64 * 16];  // 16 KB packed W2 fragments
  char* Al = (char*)Al4;
  int tid = threadIdx.x;
  int row0 = blockIdx.x * 64;
  for (int i = tid; i < 64 * 16; i += 256) Wl4[i] = ((const uint4*)Wp)[i];
  const uint4* Ab = (const uint4*)Ab16;
  for (int i = tid; i < 64 * 16; i += 256) {
    int r = i >> 4, c8 = i & 15;
    int gr = row0 + r;
    uint4 v = make_uint4(0, 0, 0, 0);
    if (gr < N_NODES) v = Ab[(uint)gr * 16u + c8];
    int byte = (r * 256 + c8 * 16) ^ ((r & 7) << 4);
    *(uint4*)(Al + byte) = v;
  }
  __syncthreads();
  int lane = tid & 63, w = tid >> 6;
  f32x4 acc[4];
#pragma unroll
  for (int ct = 0; ct < 4; ct++) acc[ct] = (f32x4){0.f, 0.f, 0.f, 0.f};
  int arow = w * 16 + (lane & 15);
#pragma unroll
  for (int ks = 0; ks < 4; ks++) {
    int abyte = (arow * 256 + ks * 64 + (lane >> 4) * 16) ^ ((arow & 7) << 4);
    short8v a = *(const short8v*)(Al + abyte);
#pragma unroll
    for (int ct = 0; ct < 4; ct++) {
      short8v bb = *(const short8v*)((const char*)Wl4 + ((ks * 4 + ct) * 64 + lane) * 16);
      acc[ct] = __builtin_amdgcn_mfma_f32_16x16x32_bf16(a, bb, acc[ct], 0, 0, 0);
    }
  }
#pragma unroll
  for (int j = 0; j < 4; j++) {
    int grow = row0 + w * 16 + ((lane >> 4) << 2) + j;
    if (grow < N_NODES) {
      float scale = dinv[grow];
#pragma unroll
      for (int ct = 0; ct < 4; ct++) {
        Cb[(uint)grow * 64u + ct * 16 + (lane & 15)] =
            (unsigned short)bfrn(acc[ct][j] * scale);
      }
    }
  }
}

// ---------------- prop, 64 bf16 feats, 8 edges/wave-load (8 lanes x uint4) --------
// Row = 128 B = 8 lanes x 16 B. grp = lane>>3 (8 edges); o8 = lane&7 (8 feats).

__global__ __launch_bounds__(256) void prop64q8_k(const uint4* __restrict__ X4,  // bf16x8
                                                  float4* __restrict__ Y4,
                                                  const int* __restrict__ off,
                                                  const uint* __restrict__ cc,
                                                  const float* __restrict__ dinv) {
  int node = blockIdx.x * 4 + (threadIdx.x >> 6);
  if (node >= N_NODES) return;
  uint lane = threadIdx.x & 63u;
  uint grp = lane >> 3, o8 = lane & 7u;
  float di = dinv[node];
  uint4 s = X4[(uint)node * 8u + o8];
  float a0 = 0.f, a1 = 0.f, a2 = 0.f, a3 = 0.f, a4 = 0.f, a5 = 0.f, a6 = 0.f, a7 = 0.f;
  int e = off[node], e1 = off[node + 1];
  for (; e + 15 < e1; e += 16) {  // 2 x 8 edges, 2 row-loads in flight
    uint c0 = cc[e + grp], c1 = cc[e + 8 + grp];
    uint4 v0 = X4[c0 * 8u + o8];
    uint4 v1 = X4[c1 * 8u + o8];
    a0 += bflo(v0.x) + bflo(v1.x);
    a1 += bfhi(v0.x) + bfhi(v1.x);
    a2 += bflo(v0.y) + bflo(v1.y);
    a3 += bfhi(v0.y) + bfhi(v1.y);
    a4 += bflo(v0.z) + bflo(v1.z);
    a5 += bfhi(v0.z) + bfhi(v1.z);
    a6 += bflo(v0.w) + bflo(v1.w);
    a7 += bfhi(v0.w) + bfhi(v1.w);
  }
  for (; e + 7 < e1; e += 8) {  // 8 edges
    uint c0 = cc[e + grp];
    uint4 v0 = X4[c0 * 8u + o8];
    a0 += bflo(v0.x); a1 += bfhi(v0.x);
    a2 += bflo(v0.y); a3 += bfhi(v0.y);
    a4 += bflo(v0.z); a5 += bfhi(v0.z);
    a6 += bflo(v0.w); a7 += bfhi(v0.w);
  }
  if (e + (int)grp < e1) {  // tail 1..7 edges: group-masked
    uint c0 = cc[e + grp];
    uint4 v0 = X4[c0 * 8u + o8];
    a0 += bflo(v0.x); a1 += bfhi(v0.x);
    a2 += bflo(v0.y); a3 += bfhi(v0.y);
    a4 += bflo(v0.z); a5 += bfhi(v0.z);
    a6 += bflo(v0.w); a7 += bfhi(v0.w);
  }
  a0 += __shfl_xor(a0, 8);  a1 += __shfl_xor(a1, 8);
  a2 += __shfl_xor(a2, 8);  a3 += __shfl_xor(a3, 8);
  a4 += __shfl_xor(a4, 8);  a5 += __shfl_xor(a5, 8);
  a6 += __shfl_xor(a6, 8);  a7 += __shfl_xor(a7, 8);
  a0 += __shfl_xor(a0, 16); a1 += __shfl_xor(a1, 16);
  a2 += __shfl_xor(a2, 16); a3 += __shfl_xor(a3, 16);
  a4 += __shfl_xor(a4, 16); a5 += __shfl_xor(a5, 16);
  a6 += __shfl_xor(a6, 16); a7 += __shfl_xor(a7, 16);
  a0 += __shfl_xor(a0, 32); a1 += __shfl_xor(a1, 32);
  a2 += __shfl_xor(a2, 32); a3 += __shfl_xor(a3, 32);
  a4 += __shfl_xor(a4, 32); a5 += __shfl_xor(a5, 32);
  a6 += __shfl_xor(a6, 32); a7 += __shfl_xor(a7, 32);
  a0 = (a0 + bflo(s.x)) * di; a1 = (a1 + bfhi(s.x)) * di;
  a2 = (a2 + bflo(s.y)) * di; a3 = (a3 + bfhi(s.y)) * di;
  a4 = (a4 + bflo(s.z)) * di; a5 = (a5 + bfhi(s.z)) * di;
  a6 = (a6 + bflo(s.w)) * di; a7 = (a7 + bfhi(s.w)) * di;
  if (lane < 8) {
    float4 o0, o1;
    o0.x = a0; o0.y = a1; o0.z = a2; o0.w = a3;
    o1.x = a4; o1.y = a5; o1.z = a6; o1.w = a7;
    Y4[(uint)node * 16u + o8 * 2 + 0] = o0;
    Y4[(uint)node * 16u + o8 * 2 + 1] = o1;
  }
}

// ---------------- launch ----------------
// Pipeline (uses (PX)W == P(XW) and D^-1/2 factoring):
//   memset gcur; combo (1024 thr): binbuf bucket-sort + W01p/W2p packs
//   buckoff (1024 thr): off/dinv/cc (CSR, LDS-staged bucket)
//   mgemm128: x0b = bf16(dinv ⊙ (feat@W01))    [MFMA]
//   prop128q: x1b = bf16(relu(dinv ⊙ gather(x0b)))
//   mgemm64:  t2b = bf16(dinv ⊙ (x1b @ W2))    [MFMA]
//   prop64q8: out = dinv ⊙ gather(t2b)          (fp32)

extern "C" void kernel_launch(void* const* d_in, const int* in_sizes, int n_in,
                              void* d_out, int out_size, void* d_ws, size_t ws_size,
                              hipStream_t stream) {
  const float* feat = (const float*)d_in[0];
  const int* ei = (const int*)d_in[1];  // int32 per harness contract
  const float* W0 = (const float*)d_in[2];
  const float* W1 = (const float*)d_in[3];
  const float* W2 = (const float*)d_in[4];
  float4* out = (float4*)d_out;

  char* ws = (char*)d_ws;
  unsigned short* x0b = (unsigned short*)ws; ws += (size_t)N_NODES * 128 * 2;  // 25.6 MB
  unsigned short* x1b = (unsigned short*)ws; ws += (size_t)N_NODES * 128 * 2;  // 25.6 MB
  unsigned short* t2b = (unsigned short*)ws; ws += (size_t)N_NODES * 64 * 2;   // 12.8 MB
  unsigned* binbuf = (unsigned*)ws;          ws += (size_t)NB * CAP * 4;       // 8.0 MB
  uint* cc = (uint*)ws;                      ws += (size_t)N_EDGES * 4;        // 6.4 MB
  float* dinv = (float*)ws;                  ws += (size_t)N_NODES * 4;
  int* off = (int*)ws;                       ws += (size_t)(N_NODES + 2) * 4;
  int* gcur = (int*)ws;                      ws += (size_t)NB * 4;
  unsigned short* W01p = (unsigned short*)ws; ws += 128 * 128 * 2;
  unsigned short* W2p = (unsigned short*)ws;  ws += 128 * 64 * 2;

  hipMemsetAsync(gcur, 0, (size_t)NB * 4, stream);
  combo_k<<<NBLK + 24, 1024, 0, stream>>>(ei, gcur, binbuf, W0, W1, W2, W01p, W2p);
  buckoff_k<<<NB, 1024, 0, stream>>>(binbuf, gcur, off, dinv, cc);
  mgemm128_k<<<(N_NODES + 63) / 64, 256, 0, stream>>>(feat, W01p, x0b, dinv);
  prop128q_k<true><<<(N_NODES + 3) / 4, 256, 0, stream>>>((const uint4*)x0b, (uint4*)x1b,
                                                          off, cc, dinv);
  mgemm64_k<<<(N_NODES + 63) / 64, 256, 0, stream>>>(x1b, W2p, t2b, dinv);
  prop64q8_k<<<(N_NODES + 3) / 4, 256, 0, stream>>>((const uint4*)t2b, out, off, cc, dinv);
}